// Round 1
// baseline (28671.906 us; speedup 1.0000x reference)
//
#include <hip/hip_runtime.h>
#include <hip/hip_fp16.h>
#include <cstdint>
#include <cstddef>

// ---------------------------------------------------------------------------
// Fused cross-modal 2-layer LSTM, B=256, S=128, H=1024, 3 modalities.
// Strategy: fp16 MFMA GEMMs (fp32 accum), gate-interleaved weight layout so
// the LSTM cell fuses into the GEMM epilogue via 4-lane shuffles; per-step
// two kernels (layer0 for all mods, layer1 for all mods); parity-double-
// buffered concat input buffers; one-time fp32->fp16 repack per call.
// ---------------------------------------------------------------------------

typedef _Float16 half8 __attribute__((ext_vector_type(8)));
typedef float floatx4 __attribute__((ext_vector_type(4)));

__device__ __forceinline__ void gload16(const void* g, void* l) {
  __builtin_amdgcn_global_load_lds(
      (const __attribute__((address_space(1))) void*)g,
      (__attribute__((address_space(3))) void*)l, 16, 0, 0);
}

__device__ __forceinline__ float fsig(float x) {
  return 1.f / (1.f + __expf(-x));
}
__device__ __forceinline__ float ftanhf(float x) {
  x = fminf(15.f, fmaxf(-15.f, x));
  float e = __expf(2.f * x);
  return (e - 1.f) / (e + 1.f);
}

struct ModParam {
  const __half* xseg; int Kx;          // x segment [256][Kx] (Kx may be 0)
  const __half* inseg; int Kin;        // h segment [256][Kin]
  const __half* W;                     // [4096][Kx+Kin], gate-interleaved rows
  const float* bias;                   // [4096] bih+bhh, gate-interleaved
  float* c;                            // [256][1024] fp32 cell state
  __half* dst0; int ds0, off0;         // h fp16 destinations (may be null)
  __half* dst1; int ds1, off1;
  __half* dst2; int ds2, off2;
  __half* feat; int featoff;           // non-null only at last step (layer 1)
};
struct PhaseParams { ModParam m[3]; };

// GEMM: C[b, n'] = sum_k In[b,k] * W[n',k], M=256, N=4096, K=Kx+Kin.
// Tile: BM=256 x BN=64, 4 waves (each 64x64 = 4x4 fragments of 16x16).
// grid = 3 modalities * 64 n-tiles = 192 blocks.
__global__ __launch_bounds__(256) void lstm_phase(PhaseParams P) {
  const int mod = blockIdx.x >> 6;
  const int bn = blockIdx.x & 63;
  const ModParam p = P.m[mod];
  const int Ktot = p.Kx + p.Kin;
  const int tid = threadIdx.x;
  const int lane = tid & 63, wid = tid >> 6;
  const int ln = lane & 15, lm = lane >> 4, c4 = lane & 3;

  __shared__ __align__(16) __half As[256][64];   // 32 KiB
  __shared__ __align__(16) __half Bs[64][64];    // 8 KiB

  floatx4 acc[4][4];
#pragma unroll
  for (int mi = 0; mi < 4; ++mi)
#pragma unroll
    for (int ni = 0; ni < 4; ++ni) acc[mi][ni] = (floatx4)0.f;

  const int nK = Ktot >> 6;
  for (int ks = 0; ks < nK; ++ks) {
    const int k0 = ks << 6;
    // --- stage A tile (256 x 64 halves = 32 KiB): 8 x 256 lanes x 16 B
    const __half* abase;
    int astr;
    if (k0 < p.Kx) { abase = p.xseg + k0; astr = p.Kx; }
    else           { abase = p.inseg + (k0 - p.Kx); astr = p.Kin; }
#pragma unroll
    for (int it = 0; it < 8; ++it) {
      int idx = it * 256 + tid;                  // 0..2047
      gload16(abase + (size_t)(idx >> 3) * astr + (idx & 7) * 8,
              ((__half*)As) + (size_t)idx * 8);
    }
    // --- stage B tile (64 x 64): 2 x 256 x 16 B
    const __half* bbase = p.W + (size_t)bn * 64 * Ktot + k0;
#pragma unroll
    for (int it = 0; it < 2; ++it) {
      int idx = it * 256 + tid;                  // 0..511
      gload16(bbase + (size_t)(idx >> 3) * Ktot + (idx & 7) * 8,
              ((__half*)Bs) + (size_t)idx * 8);
    }
    __syncthreads();
#pragma unroll
    for (int kh = 0; kh < 2; ++kh) {
      half8 av[4], bv[4];
#pragma unroll
      for (int mi = 0; mi < 4; ++mi)
        av[mi] = *(const half8*)&As[wid * 64 + mi * 16 + ln][kh * 32 + lm * 8];
#pragma unroll
      for (int ni = 0; ni < 4; ++ni)
        bv[ni] = *(const half8*)&Bs[ni * 16 + ln][kh * 32 + lm * 8];
#pragma unroll
      for (int mi = 0; mi < 4; ++mi)
#pragma unroll
        for (int ni = 0; ni < 4; ++ni)
          acc[mi][ni] = __builtin_amdgcn_mfma_f32_16x16x32_f16(
              av[mi], bv[ni], acc[mi][ni], 0, 0, 0);
    }
    __syncthreads();
  }

  // --- fused LSTM cell epilogue ---
  // n' = j*4 + gate (gate: 0=i,1=f,2=g,3=o). 4 gates of hidden j sit in the
  // 4 adjacent lanes of an aligned group -> 3 shfl_xor reconstruct them.
  const int nbase = bn * 64;
#pragma unroll
  for (int ni = 0; ni < 4; ++ni) {
    const int ncol = nbase + ni * 16 + ln;
    const float bia = p.bias[ncol];
    const int j = ncol >> 2;                     // same for the 4-lane group
#pragma unroll
    for (int mi = 0; mi < 4; ++mi) {
#pragma unroll
      for (int r = 0; r < 4; ++r) {
        float v = acc[mi][ni][r] + bia;
        float g1 = __shfl_xor(v, 1);
        float g2 = __shfl_xor(v, 2);
        float g3 = __shfl_xor(v, 3);
        // value at group position q is from lane xor-mask (c4^q)
        int m0 = c4 ^ 0, m1 = c4 ^ 1, m2 = c4 ^ 2, m3 = c4 ^ 3;
        float zi = m0 == 0 ? v : (m0 == 1 ? g1 : (m0 == 2 ? g2 : g3));
        float zf = m1 == 0 ? v : (m1 == 1 ? g1 : (m1 == 2 ? g2 : g3));
        float zg = m2 == 0 ? v : (m2 == 1 ? g1 : (m2 == 2 ? g2 : g3));
        float zo = m3 == 0 ? v : (m3 == 1 ? g1 : (m3 == 2 ? g2 : g3));
        const int b = wid * 64 + mi * 16 + lm * 4 + r;
        float cp = p.c[b * 1024 + j];
        float cn = fsig(zf) * cp + fsig(zi) * ftanhf(zg);
        float hn = fsig(zo) * ftanhf(cn);
        __half h16 = __float2half(hn);
        if (c4 == 0) {
          if (p.dst0) p.dst0[(size_t)b * p.ds0 + p.off0 + j] = h16;
        } else if (c4 == 1) {
          if (p.dst1) p.dst1[(size_t)b * p.ds1 + p.off1 + j] = h16;
        } else if (c4 == 2) {
          if (p.dst2) p.dst2[(size_t)b * p.ds2 + p.off2 + j] = h16;
        } else {
          p.c[b * 1024 + j] = cn;
          if (p.feat) p.feat[(size_t)b * 3072 + p.featoff + j] = h16;
        }
      }
    }
  }
}

// Repack weights fp32->fp16, gate-interleaved rows (n' = j*4+g), column
// layout [x (padded to fpad) | ih-h part (hih) | hh (1024)]. Also packs bias.
__global__ void pack_w(__half* dst, const float* Wih, const float* Whh,
                       float* bdst, const float* bih, const float* bhh,
                       int f, int fpad, int hih, int Ktot) {
  long long i = (long long)blockIdx.x * 256 + threadIdx.x;
  long long tot = (long long)4096 * Ktot;
  if (i < tot) {
    int n = (int)(i / Ktot), k = (int)(i % Ktot);
    int nsrc = (n & 3) * 1024 + (n >> 2);
    float v;
    if (k < fpad)
      v = (k < f) ? Wih[(size_t)nsrc * (f + hih) + k] : 0.f;
    else if (k < fpad + hih)
      v = Wih[(size_t)nsrc * (f + hih) + f + (k - fpad)];
    else
      v = Whh[(size_t)nsrc * 1024 + (k - fpad - hih)];
    dst[i] = __float2half(v);
  }
  if (i < 4096) {
    int nsrc = ((int)i & 3) * 1024 + ((int)i >> 2);
    bdst[i] = bih[nsrc] + bhh[nsrc];
  }
}

// x [B=256][S=128][f] fp32 -> [S][B][fpad] fp16, zero-padded cols.
__global__ void pack_x(__half* dst, const float* x, int f, int fpad) {
  long long i = (long long)blockIdx.x * 256 + threadIdx.x;
  long long tot = (long long)128 * 256 * fpad;
  if (i >= tot) return;
  int k = (int)(i % fpad);
  long long r = i / fpad;
  int b = (int)(r % 256);
  int t = (int)(r / 256);
  dst[i] = (k < f) ? __float2half(x[((size_t)b * 128 + t) * f + k])
                   : __float2half(0.f);
}

// out[b] = feat[b,:] . Wd + bd
__global__ void final_dot(const __half* feat, const float* Wd, const float* bd,
                          float* out) {
  int b = blockIdx.x, tid = threadIdx.x;
  float s = 0.f;
  for (int j = tid; j < 3072; j += 256)
    s += __half2float(feat[(size_t)b * 3072 + j]) * Wd[j];
  __shared__ float red[256];
  red[tid] = s;
  __syncthreads();
  for (int o = 128; o > 0; o >>= 1) {
    if (tid < o) red[tid] += red[tid + o];
    __syncthreads();
  }
  if (tid == 0) out[b] = red[0] + bd[0];
}

extern "C" void kernel_launch(void* const* d_in, const int* in_sizes, int n_in,
                              void* d_out, int out_size, void* d_ws, size_t ws_size,
                              hipStream_t stream) {
  const int B = 256, S = 128, H = 1024, NG = 4096;
  const int FRAW[3] = {300, 35, 74};
  const int FPAD[3] = {320, 64, 128};

  const float* xin[3] = {(const float*)d_in[0], (const float*)d_in[1],
                         (const float*)d_in[2]};
  const float *Wih0[3], *Whh0[3], *bih0[3], *bhh0[3];
  const float *Wih1[3], *Whh1[3], *bih1[3], *bhh1[3];
  for (int m = 0; m < 3; ++m) {
    int bidx = 3 + m * 8;
    Wih0[m] = (const float*)d_in[bidx + 0];
    Whh0[m] = (const float*)d_in[bidx + 1];
    bih0[m] = (const float*)d_in[bidx + 2];
    bhh0[m] = (const float*)d_in[bidx + 3];
    Wih1[m] = (const float*)d_in[bidx + 4];
    Whh1[m] = (const float*)d_in[bidx + 5];
    bih1[m] = (const float*)d_in[bidx + 6];
    bhh1[m] = (const float*)d_in[bidx + 7];
  }
  const float* Wd = (const float*)d_in[27];
  const float* bd = (const float*)d_in[28];

  uint8_t* wsb = (uint8_t*)d_ws;
  size_t off = 0;
  auto alloc = [&](size_t bytes) -> void* {
    void* p = wsb + off;
    off += (bytes + 255) & ~(size_t)255;
    return p;
  };

  __half* W0[3];
  __half* W1[3];
  int K0[3];
  for (int m = 0; m < 3; ++m) {
    K0[m] = FPAD[m] + 3 * H;
    W0[m] = (__half*)alloc((size_t)NG * K0[m] * 2);
  }
  for (int m = 0; m < 3; ++m) W1[m] = (__half*)alloc((size_t)NG * 2 * H * 2);
  float* biasB = (float*)alloc((size_t)6 * NG * 4);
  __half* X16[3];
  for (int m = 0; m < 3; ++m)
    X16[m] = (__half*)alloc((size_t)S * B * FPAD[m] * 2);
  size_t stateStart = off;
  __half* In0[3];
  __half* In1[3];
  for (int m = 0; m < 3; ++m) In0[m] = (__half*)alloc((size_t)2 * B * 3072 * 2);
  for (int m = 0; m < 3; ++m) In1[m] = (__half*)alloc((size_t)2 * B * 2048 * 2);
  float* cbuf = (float*)alloc((size_t)6 * B * H * 4);
  size_t stateEnd = off;
  __half* featB = (__half*)alloc((size_t)B * 3072 * 2);

  if (off > ws_size) return;  // workspace too small: fail loudly via mismatch

  // ---- one-time prep (runs every call; deterministic) ----
  for (int m = 0; m < 3; ++m) {
    long long tot0 = (long long)NG * K0[m];
    pack_w<<<dim3((unsigned)((tot0 + 255) / 256)), 256, 0, stream>>>(
        W0[m], Wih0[m], Whh0[m], biasB + m * NG, bih0[m], bhh0[m],
        FRAW[m], FPAD[m], 2 * H, K0[m]);
    long long tot1 = (long long)NG * 2 * H;
    pack_w<<<dim3((unsigned)((tot1 + 255) / 256)), 256, 0, stream>>>(
        W1[m], Wih1[m], Whh1[m], biasB + (3 + m) * NG, bih1[m], bhh1[m],
        0, 0, H, 2 * H);
    long long totx = (long long)S * B * FPAD[m];
    pack_x<<<dim3((unsigned)((totx + 255) / 256)), 256, 0, stream>>>(
        X16[m], xin[m], FRAW[m], FPAD[m]);
  }
  hipMemsetAsync(wsb + stateStart, 0, stateEnd - stateStart, stream);

  // ---- recurrent loop: 2 phase kernels per step ----
  for (int t = 0; t < S; ++t) {
    int pq = t & 1;
    __half* in0cur[3], *in0nxt[3], *in1cur[3], *in1nxt[3];
    for (int m = 0; m < 3; ++m) {
      in0cur[m] = In0[m] + (size_t)pq * B * 3072;
      in0nxt[m] = In0[m] + (size_t)(pq ^ 1) * B * 3072;
      in1cur[m] = In1[m] + (size_t)pq * B * 2048;
      in1nxt[m] = In1[m] + (size_t)(pq ^ 1) * B * 2048;
    }

    PhaseParams PA;
    for (int m = 0; m < 3; ++m) {
      ModParam& q = PA.m[m];
      q.xseg = X16[m] + (size_t)t * B * FPAD[m];
      q.Kx = FPAD[m];
      q.inseg = in0cur[m];
      q.Kin = 3072;
      q.W = W0[m];
      q.bias = biasB + m * NG;
      q.c = cbuf + (size_t)m * B * H;
      q.dst0 = in1cur[m]; q.ds0 = 2048; q.off0 = 0;      // -> layer1 input (this step)
      q.dst1 = in0nxt[m]; q.ds1 = 3072; q.off1 = 2048;   // -> own h0 slot (next step)
      q.dst2 = nullptr;   q.ds2 = 0;    q.off2 = 0;
      q.feat = nullptr;   q.featoff = 0;
    }
    lstm_phase<<<dim3(192), 256, 0, stream>>>(PA);

    PhaseParams PB;
    for (int m = 0; m < 3; ++m) {
      ModParam& q = PB.m[m];
      q.xseg = nullptr; q.Kx = 0;
      q.inseg = in1cur[m]; q.Kin = 2048;
      q.W = W1[m];
      q.bias = biasB + (3 + m) * NG;
      q.c = cbuf + (size_t)(3 + m) * B * H;
      q.feat = (t == S - 1) ? featB : nullptr;
      q.featoff = m * H;
      q.ds0 = 3072; q.ds1 = 3072; q.ds2 = 2048;
      if (m == 0) {        // h1_t -> In0_v[:,0], In0_a[:,0], In1_t[:,1024]
        q.dst0 = in0nxt[1]; q.off0 = 0;
        q.dst1 = in0nxt[2]; q.off1 = 0;
        q.dst2 = in1nxt[0]; q.off2 = 1024;
      } else if (m == 1) { // h1_v -> In0_t[:,0], In0_a[:,1024], In1_v[:,1024]
        q.dst0 = in0nxt[0]; q.off0 = 0;
        q.dst1 = in0nxt[2]; q.off1 = 1024;
        q.dst2 = in1nxt[1]; q.off2 = 1024;
      } else {             // h1_a -> In0_t[:,1024], In0_v[:,1024], In1_a[:,1024]
        q.dst0 = in0nxt[0]; q.off0 = 1024;
        q.dst1 = in0nxt[1]; q.off1 = 1024;
        q.dst2 = in1nxt[2]; q.off2 = 1024;
      }
    }
    lstm_phase<<<dim3(192), 256, 0, stream>>>(PB);
  }

  final_dot<<<dim3(256), 256, 0, stream>>>(featB, Wd, bd, (float*)d_out);
}

// Round 2
// 10824.048 us; speedup vs baseline: 2.6489x; 2.6489x over previous
//
#include <hip/hip_runtime.h>
#include <hip/hip_fp16.h>
#include <cstdint>
#include <cstddef>

// ---------------------------------------------------------------------------
// Fused cross-modal 2-layer LSTM, B=256, S=128, H=1024, 3 modalities.
// v2: 64x64 blocks (4 waves of 32x32), grid=768 (=3 blocks/CU, launch_bounds
// (256,3)), XOR-chunk LDS swizzle (linear global_load_lds dest + inverse-
// swizzled source + swizzled ds_read), XCD-grouped M-tile siblings so weight
// strips get L2 reuse. fp16 MFMA (fp32 accum), gate-interleaved weights,
// LSTM cell fused into GEMM epilogue via 4-lane shuffles.
// ---------------------------------------------------------------------------

typedef _Float16 half8 __attribute__((ext_vector_type(8)));
typedef float floatx4 __attribute__((ext_vector_type(4)));

__device__ __forceinline__ void gload16(const void* g, void* l) {
  __builtin_amdgcn_global_load_lds(
      (const __attribute__((address_space(1))) void*)g,
      (__attribute__((address_space(3))) void*)l, 16, 0, 0);
}

__device__ __forceinline__ float fsig(float x) {
  return 1.f / (1.f + __expf(-x));
}
__device__ __forceinline__ float ftanhf(float x) {
  x = fminf(15.f, fmaxf(-15.f, x));
  float e = __expf(2.f * x);
  return (e - 1.f) / (e + 1.f);
}

struct ModParam {
  const __half* xseg; int Kx;          // x segment [256][Kx] (Kx may be 0)
  const __half* inseg; int Kin;        // h segment [256][Kin]
  const __half* W;                     // [4096][Kx+Kin], gate-interleaved rows
  const float* bias;                   // [4096] bih+bhh, gate-interleaved
  float* c;                            // [256][1024] fp32 cell state
  __half* dst0; int ds0, off0;         // h fp16 destinations (may be null)
  __half* dst1; int ds1, off1;
  __half* dst2; int ds2, off2;
  __half* feat; int featoff;           // non-null only at last step (layer 1)
};
struct PhaseParams { ModParam m[3]; };

// GEMM: C[b, n'] = sum_k In[b,k] * W[n',k], M=256, N=4096 per modality.
// Block tile: 64 (M) x 64 (N), 4 waves in 2x2, each wave 32x32 (2x2 frags).
// grid = 8 xcd-slots * 96 rounds = 768 blocks = 3 blocks/CU.
// Work mapping groups the 4 M-tile siblings of one (mod,bn) weight strip
// onto one XCD slot (consecutive rounds) for L2 weight reuse.
__global__ __launch_bounds__(256, 3) void lstm_phase(PhaseParams P) {
  const int b_ = blockIdx.x;
  const int xcd = b_ & 7, rnd = b_ >> 3;          // 8 slots x 96 rounds
  const int pairIdx = xcd * 24 + (rnd >> 2);      // 0..191 = (mod, bn)
  const int mtile = rnd & 3;
  const int mod = pairIdx >> 6;
  const int bn = pairIdx & 63;
  const ModParam p = P.m[mod];
  const int Ktot = p.Kx + p.Kin;
  const int tid = threadIdx.x;
  const int lane = tid & 63, wid = tid >> 6;
  const int ln = lane & 15, lm = lane >> 4, c4 = lane & 3;
  const int wr = wid >> 1, wc = wid & 1;          // wave 2x2 grid

  __shared__ __align__(16) __half As[64][64];     // 8 KiB
  __shared__ __align__(16) __half Bs[64][64];     // 8 KiB

  floatx4 acc[2][2];
#pragma unroll
  for (int mi = 0; mi < 2; ++mi)
#pragma unroll
    for (int ni = 0; ni < 2; ++ni) acc[mi][ni] = (floatx4)0.f;

  const int nK = Ktot >> 6;
  for (int ks = 0; ks < nK; ++ks) {
    const int k0 = ks << 6;
    // --- stage A tile (64 x 64 halves = 8 KiB): 2 x 256 lanes x 16 B.
    // LDS dest linear (global_load_lds requirement); SOURCE chunk index is
    // XOR-swizzled so the ds_read side can use the same involution.
    const __half* abase;
    int astr;
    if (k0 < p.Kx) { abase = p.xseg + k0; astr = p.Kx; }
    else           { abase = p.inseg + (k0 - p.Kx); astr = p.Kin; }
#pragma unroll
    for (int it = 0; it < 2; ++it) {
      int idx = it * 256 + tid;                   // 0..511
      int row = idx >> 3, pc = idx & 7;
      int lc = pc ^ (row & 7);                    // logical chunk
      gload16(abase + (size_t)(mtile * 64 + row) * astr + lc * 8,
              ((__half*)As) + (size_t)idx * 8);
    }
    // --- stage B tile (64 x 64)
    const __half* bbase = p.W + (size_t)(bn * 64) * Ktot + k0;
#pragma unroll
    for (int it = 0; it < 2; ++it) {
      int idx = it * 256 + tid;
      int row = idx >> 3, pc = idx & 7;
      int lc = pc ^ (row & 7);
      gload16(bbase + (size_t)row * Ktot + lc * 8,
              ((__half*)Bs) + (size_t)idx * 8);
    }
    __syncthreads();
#pragma unroll
    for (int kh = 0; kh < 2; ++kh) {
      half8 av[2], bv[2];
#pragma unroll
      for (int mi = 0; mi < 2; ++mi) {
        int row = wr * 32 + mi * 16 + ln;
        int ch = (kh * 4 + lm) ^ (row & 7);       // swizzled read
        av[mi] = *(const half8*)&As[row][ch * 8];
      }
#pragma unroll
      for (int ni = 0; ni < 2; ++ni) {
        int row = wc * 32 + ni * 16 + ln;
        int ch = (kh * 4 + lm) ^ (row & 7);
        bv[ni] = *(const half8*)&Bs[row][ch * 8];
      }
#pragma unroll
      for (int mi = 0; mi < 2; ++mi)
#pragma unroll
        for (int ni = 0; ni < 2; ++ni)
          acc[mi][ni] = __builtin_amdgcn_mfma_f32_16x16x32_f16(
              av[mi], bv[ni], acc[mi][ni], 0, 0, 0);
    }
    __syncthreads();
  }

  // --- fused LSTM cell epilogue ---
  // n' = j*4 + gate (0=i,1=f,2=g,3=o): 4 gates of hidden j sit in 4 adjacent
  // lanes of an aligned group -> 3 shfl_xor reconstruct them.
#pragma unroll
  for (int ni = 0; ni < 2; ++ni) {
    const int ncol = bn * 64 + wc * 32 + ni * 16 + ln;
    const float bia = p.bias[ncol];
    const int j = ncol >> 2;
#pragma unroll
    for (int mi = 0; mi < 2; ++mi) {
#pragma unroll
      for (int r = 0; r < 4; ++r) {
        float v = acc[mi][ni][r] + bia;
        float g1 = __shfl_xor(v, 1);
        float g2 = __shfl_xor(v, 2);
        float g3 = __shfl_xor(v, 3);
        int m0 = c4 ^ 0, m1 = c4 ^ 1, m2 = c4 ^ 2, m3 = c4 ^ 3;
        float zi = m0 == 0 ? v : (m0 == 1 ? g1 : (m0 == 2 ? g2 : g3));
        float zf = m1 == 0 ? v : (m1 == 1 ? g1 : (m1 == 2 ? g2 : g3));
        float zg = m2 == 0 ? v : (m2 == 1 ? g1 : (m2 == 2 ? g2 : g3));
        float zo = m3 == 0 ? v : (m3 == 1 ? g1 : (m3 == 2 ? g2 : g3));
        const int b = mtile * 64 + wr * 32 + mi * 16 + lm * 4 + r;
        float cp = p.c[b * 1024 + j];
        float cn = fsig(zf) * cp + fsig(zi) * ftanhf(zg);
        float hn = fsig(zo) * ftanhf(cn);
        __half h16 = __float2half(hn);
        if (c4 == 0) {
          if (p.dst0) p.dst0[(size_t)b * p.ds0 + p.off0 + j] = h16;
        } else if (c4 == 1) {
          if (p.dst1) p.dst1[(size_t)b * p.ds1 + p.off1 + j] = h16;
        } else if (c4 == 2) {
          if (p.dst2) p.dst2[(size_t)b * p.ds2 + p.off2 + j] = h16;
        } else {
          p.c[b * 1024 + j] = cn;
          if (p.feat) p.feat[(size_t)b * 3072 + p.featoff + j] = h16;
        }
      }
    }
  }
}

// Repack weights fp32->fp16, gate-interleaved rows (n' = j*4+g), column
// layout [x (padded to fpad) | ih-h part (hih) | hh (1024)]. Also packs bias.
__global__ void pack_w(__half* dst, const float* Wih, const float* Whh,
                       float* bdst, const float* bih, const float* bhh,
                       int f, int fpad, int hih, int Ktot) {
  long long i = (long long)blockIdx.x * 256 + threadIdx.x;
  long long tot = (long long)4096 * Ktot;
  if (i < tot) {
    int n = (int)(i / Ktot), k = (int)(i % Ktot);
    int nsrc = (n & 3) * 1024 + (n >> 2);
    float v;
    if (k < fpad)
      v = (k < f) ? Wih[(size_t)nsrc * (f + hih) + k] : 0.f;
    else if (k < fpad + hih)
      v = Wih[(size_t)nsrc * (f + hih) + f + (k - fpad)];
    else
      v = Whh[(size_t)nsrc * 1024 + (k - fpad - hih)];
    dst[i] = __float2half(v);
  }
  if (i < 4096) {
    int nsrc = ((int)i & 3) * 1024 + ((int)i >> 2);
    bdst[i] = bih[nsrc] + bhh[nsrc];
  }
}

// x [B=256][S=128][f] fp32 -> [S][B][fpad] fp16, zero-padded cols.
__global__ void pack_x(__half* dst, const float* x, int f, int fpad) {
  long long i = (long long)blockIdx.x * 256 + threadIdx.x;
  long long tot = (long long)128 * 256 * fpad;
  if (i >= tot) return;
  int k = (int)(i % fpad);
  long long r = i / fpad;
  int b = (int)(r % 256);
  int t = (int)(r / 256);
  dst[i] = (k < f) ? __float2half(x[((size_t)b * 128 + t) * f + k])
                   : __float2half(0.f);
}

// out[b] = feat[b,:] . Wd + bd
__global__ void final_dot(const __half* feat, const float* Wd, const float* bd,
                          float* out) {
  int b = blockIdx.x, tid = threadIdx.x;
  float s = 0.f;
  for (int j = tid; j < 3072; j += 256)
    s += __half2float(feat[(size_t)b * 3072 + j]) * Wd[j];
  __shared__ float red[256];
  red[tid] = s;
  __syncthreads();
  for (int o = 128; o > 0; o >>= 1) {
    if (tid < o) red[tid] += red[tid + o];
    __syncthreads();
  }
  if (tid == 0) out[b] = red[0] + bd[0];
}

extern "C" void kernel_launch(void* const* d_in, const int* in_sizes, int n_in,
                              void* d_out, int out_size, void* d_ws, size_t ws_size,
                              hipStream_t stream) {
  const int B = 256, S = 128, H = 1024, NG = 4096;
  const int FRAW[3] = {300, 35, 74};
  const int FPAD[3] = {320, 64, 128};

  const float* xin[3] = {(const float*)d_in[0], (const float*)d_in[1],
                         (const float*)d_in[2]};
  const float *Wih0[3], *Whh0[3], *bih0[3], *bhh0[3];
  const float *Wih1[3], *Whh1[3], *bih1[3], *bhh1[3];
  for (int m = 0; m < 3; ++m) {
    int bidx = 3 + m * 8;
    Wih0[m] = (const float*)d_in[bidx + 0];
    Whh0[m] = (const float*)d_in[bidx + 1];
    bih0[m] = (const float*)d_in[bidx + 2];
    bhh0[m] = (const float*)d_in[bidx + 3];
    Wih1[m] = (const float*)d_in[bidx + 4];
    Whh1[m] = (const float*)d_in[bidx + 5];
    bih1[m] = (const float*)d_in[bidx + 6];
    bhh1[m] = (const float*)d_in[bidx + 7];
  }
  const float* Wd = (const float*)d_in[27];
  const float* bd = (const float*)d_in[28];

  uint8_t* wsb = (uint8_t*)d_ws;
  size_t off = 0;
  auto alloc = [&](size_t bytes) -> void* {
    void* p = wsb + off;
    off += (bytes + 255) & ~(size_t)255;
    return p;
  };

  __half* W0[3];
  __half* W1[3];
  int K0[3];
  for (int m = 0; m < 3; ++m) {
    K0[m] = FPAD[m] + 3 * H;
    W0[m] = (__half*)alloc((size_t)NG * K0[m] * 2);
  }
  for (int m = 0; m < 3; ++m) W1[m] = (__half*)alloc((size_t)NG * 2 * H * 2);
  float* biasB = (float*)alloc((size_t)6 * NG * 4);
  __half* X16[3];
  for (int m = 0; m < 3; ++m)
    X16[m] = (__half*)alloc((size_t)S * B * FPAD[m] * 2);
  size_t stateStart = off;
  __half* In0[3];
  __half* In1[3];
  for (int m = 0; m < 3; ++m) In0[m] = (__half*)alloc((size_t)2 * B * 3072 * 2);
  for (int m = 0; m < 3; ++m) In1[m] = (__half*)alloc((size_t)2 * B * 2048 * 2);
  float* cbuf = (float*)alloc((size_t)6 * B * H * 4);
  size_t stateEnd = off;
  __half* featB = (__half*)alloc((size_t)B * 3072 * 2);

  if (off > ws_size) return;  // workspace too small: fail loudly via mismatch

  // ---- one-time prep (runs every call; deterministic) ----
  for (int m = 0; m < 3; ++m) {
    long long tot0 = (long long)NG * K0[m];
    pack_w<<<dim3((unsigned)((tot0 + 255) / 256)), 256, 0, stream>>>(
        W0[m], Wih0[m], Whh0[m], biasB + m * NG, bih0[m], bhh0[m],
        FRAW[m], FPAD[m], 2 * H, K0[m]);
    long long tot1 = (long long)NG * 2 * H;
    pack_w<<<dim3((unsigned)((tot1 + 255) / 256)), 256, 0, stream>>>(
        W1[m], Wih1[m], Whh1[m], biasB + (3 + m) * NG, bih1[m], bhh1[m],
        0, 0, H, 2 * H);
    long long totx = (long long)S * B * FPAD[m];
    pack_x<<<dim3((unsigned)((totx + 255) / 256)), 256, 0, stream>>>(
        X16[m], xin[m], FRAW[m], FPAD[m]);
  }
  hipMemsetAsync(wsb + stateStart, 0, stateEnd - stateStart, stream);

  // ---- recurrent loop: 2 phase kernels per step ----
  for (int t = 0; t < S; ++t) {
    int pq = t & 1;
    __half* in0cur[3], *in0nxt[3], *in1cur[3], *in1nxt[3];
    for (int m = 0; m < 3; ++m) {
      in0cur[m] = In0[m] + (size_t)pq * B * 3072;
      in0nxt[m] = In0[m] + (size_t)(pq ^ 1) * B * 3072;
      in1cur[m] = In1[m] + (size_t)pq * B * 2048;
      in1nxt[m] = In1[m] + (size_t)(pq ^ 1) * B * 2048;
    }

    PhaseParams PA;
    for (int m = 0; m < 3; ++m) {
      ModParam& q = PA.m[m];
      q.xseg = X16[m] + (size_t)t * B * FPAD[m];
      q.Kx = FPAD[m];
      q.inseg = in0cur[m];
      q.Kin = 3072;
      q.W = W0[m];
      q.bias = biasB + m * NG;
      q.c = cbuf + (size_t)m * B * H;
      q.dst0 = in1cur[m]; q.ds0 = 2048; q.off0 = 0;      // -> layer1 input (this step)
      q.dst1 = in0nxt[m]; q.ds1 = 3072; q.off1 = 2048;   // -> own h0 slot (next step)
      q.dst2 = nullptr;   q.ds2 = 0;    q.off2 = 0;
      q.feat = nullptr;   q.featoff = 0;
    }
    lstm_phase<<<dim3(768), 256, 0, stream>>>(PA);

    PhaseParams PB;
    for (int m = 0; m < 3; ++m) {
      ModParam& q = PB.m[m];
      q.xseg = nullptr; q.Kx = 0;
      q.inseg = in1cur[m]; q.Kin = 2048;
      q.W = W1[m];
      q.bias = biasB + (3 + m) * NG;
      q.c = cbuf + (size_t)(3 + m) * B * H;
      q.feat = (t == S - 1) ? featB : nullptr;
      q.featoff = m * H;
      q.ds0 = 3072; q.ds1 = 3072; q.ds2 = 2048;
      if (m == 0) {        // h1_t -> In0_v[:,0], In0_a[:,0], In1_t[:,1024]
        q.dst0 = in0nxt[1]; q.off0 = 0;
        q.dst1 = in0nxt[2]; q.off1 = 0;
        q.dst2 = in1nxt[0]; q.off2 = 1024;
      } else if (m == 1) { // h1_v -> In0_t[:,0], In0_a[:,1024], In1_v[:,1024]
        q.dst0 = in0nxt[0]; q.off0 = 0;
        q.dst1 = in0nxt[2]; q.off1 = 1024;
        q.dst2 = in1nxt[1]; q.off2 = 1024;
      } else {             // h1_a -> In0_t[:,1024], In0_v[:,1024], In1_a[:,1024]
        q.dst0 = in0nxt[0]; q.off0 = 1024;
        q.dst1 = in0nxt[1]; q.off1 = 1024;
        q.dst2 = in1nxt[2]; q.off2 = 1024;
      }
    }
    lstm_phase<<<dim3(768), 256, 0, stream>>>(PB);
  }

  final_dot<<<dim3(256), 256, 0, stream>>>(featB, Wd, bd, (float*)d_out);
}

// Round 3
// 9950.143 us; speedup vs baseline: 2.8816x; 1.0878x over previous
//
#include <hip/hip_runtime.h>
#include <hip/hip_fp16.h>
#include <cstdint>
#include <cstddef>

// ---------------------------------------------------------------------------
// Fused cross-modal 2-layer LSTM, B=256, S=128, H=1024, 3 modalities.
// v3: 64x64 blocks with K-split-4 (each wave = full 64x64 tile over a K128
// quarter, 4x4 fragments), cross-wave LDS reduction; weights pre-packed into
// MFMA-fragment order and streamed global->VGPR (no LDS for B); activations
// in chunked [K/8][256][8] layout staged via global_load_lds double-buffer.
// fp16 MFMA fp32-accum; LSTM cell fused in epilogue via 4-lane shuffles.
// ---------------------------------------------------------------------------

typedef _Float16 half8 __attribute__((ext_vector_type(8)));
typedef float floatx4 __attribute__((ext_vector_type(4)));

__device__ __forceinline__ void gload16(const void* g, void* l) {
  __builtin_amdgcn_global_load_lds(
      (const __attribute__((address_space(1))) void*)g,
      (__attribute__((address_space(3))) void*)l, 16, 0, 0);
}

__device__ __forceinline__ float fsig(float x) {
  return 1.f / (1.f + __expf(-x));
}
__device__ __forceinline__ float ftanhf(float x) {
  x = fminf(15.f, fmaxf(-15.f, x));
  float e = __expf(2.f * x);
  return (e - 1.f) / (e + 1.f);
}

struct ModParam {
  const __half* xseg;   // chunked [Kx/8][256][8] (null if Kx==0)
  const __half* inseg;  // chunked [Kin/8][256][8]
  const __half* W;      // frag-packed [64][nKt][4 wid][4 ni][64 lane][8]
  const float* bias;    // [4096] gate-interleaved (bih+bhh)
  float* c;             // [256][1024] fp32 cell state
  __half* dst0; __half* dst1; __half* dst2;  // chunked h dests (may be null)
  int off0, off1, off2; // column offsets (multiples of 1024)
  __half* feat; int featoff;  // linear [256][3072]; last step only
  int Kx, Kin;
};
struct PhaseParams { ModParam m[3]; };

// C[b,n'] = sum_k In[b,k] * W[n',k];  M=256, N=4096 per modality.
// Block = 64(M) x 64(N); 4 waves K-split a K128 staged tile (wave w takes
// k-quarter w); 4x4 16x16x32 fragments per wave; LDS reduce; fused cell.
// grid = 8 xcd-slots * 96 = 768 blocks = 3 blocks/CU.
__global__ __launch_bounds__(256, 3) void lstm_phase(PhaseParams P) {
  const int b_ = blockIdx.x;
  const int xcd = b_ & 7, rnd = b_ >> 3;
  const int pairIdx = xcd * 24 + (rnd >> 2);   // 0..191 = (mod, bn)
  const int mt = rnd & 3;
  const int mod = pairIdx >> 6;
  const int bn = pairIdx & 63;
  const ModParam p = P.m[mod];
  const int nKt = (p.Kx + p.Kin) >> 7;
  const int KxT = p.Kx >> 7;
  const int tid = threadIdx.x;
  const int lane = tid & 63, wid = tid >> 6;
  const int ln = lane & 15, lm = lane >> 4, c4 = lane & 3;

  __shared__ __align__(16) __half smem[2][1024][8];  // two 16 KiB A buffers

  floatx4 acc[4][4];
#pragma unroll
  for (int a = 0; a < 4; ++a)
#pragma unroll
    for (int b = 0; b < 4; ++b) acc[a][b] = (floatx4)0.f;

  half8 bvA[4], bvB[4];

  auto stageA = [&](int kt, int buf) {
    const __half* base; int kq0;
    if (kt < KxT) { base = p.xseg;  kq0 = kt * 16; }
    else          { base = p.inseg; kq0 = (kt - KxT) * 16; }
#pragma unroll
    for (int it = 0; it < 4; ++it) {
      int idx = it * 256 + tid;                 // chunk id 0..1023
      int kql = idx >> 6, bl = idx & 63;
      gload16(base + ((size_t)(kq0 + kql) * 256 + mt * 64 + bl) * 8,
              &smem[buf][idx][0]);
    }
  };
  auto loadB = [&](int kt, half8 (&bv)[4]) {
    const __half* src =
        p.W + ((size_t)(bn * nKt + kt) * 4 + wid) * 2048 + lane * 8;
#pragma unroll
    for (int ni = 0; ni < 4; ++ni) bv[ni] = *(const half8*)(src + ni * 512);
  };
  auto compute = [&](int buf, const half8 (&bv)[4]) {
    half8 av[4];
    const int kq = wid * 4 + lm;
#pragma unroll
    for (int mi = 0; mi < 4; ++mi)
      av[mi] = *(const half8*)&smem[buf][kq * 64 + mi * 16 + ln][0];
#pragma unroll
    for (int mi = 0; mi < 4; ++mi)
#pragma unroll
      for (int ni = 0; ni < 4; ++ni)
        acc[mi][ni] = __builtin_amdgcn_mfma_f32_16x16x32_f16(
            av[mi], bv[ni], acc[mi][ni], 0, 0, 0);
  };

  loadB(0, bvA);
  stageA(0, 0);
  __syncthreads();
  int kt = 0;
  while (true) {
    if (kt + 1 < nKt) { loadB(kt + 1, bvB); stageA(kt + 1, 1); }
    compute(0, bvA);
    __syncthreads();
    if (++kt >= nKt) break;
    if (kt + 1 < nKt) { loadB(kt + 1, bvA); stageA(kt + 1, 0); }
    compute(1, bvB);
    __syncthreads();
    if (++kt >= nKt) break;
  }

  // ---- cross-wave K-reduction (acc summed over the 4 waves) ----
  // rbuf[h(2)][ni(4)][w(4)][lane(64)] of floatx4 = 32 KiB (reuses smem).
  floatx4* rbuf = (floatx4*)&smem[0][0][0];
  auto slot = [&](int h, int ni, int w) {
    return ((h * 4 + ni) * 4 + w) * 64 + lane;
  };
  floatx4 own[4];
#pragma unroll
  for (int ni = 0; ni < 4; ++ni) {
    rbuf[slot(0, ni, wid)] = acc[0][ni];
    rbuf[slot(1, ni, wid)] = acc[1][ni];
  }
  __syncthreads();
  if (wid == 0) {
#pragma unroll
    for (int ni = 0; ni < 4; ++ni)
      own[ni] = acc[0][ni] + rbuf[slot(0, ni, 1)] + rbuf[slot(0, ni, 2)] +
                rbuf[slot(0, ni, 3)];
  } else if (wid == 1) {
#pragma unroll
    for (int ni = 0; ni < 4; ++ni)
      own[ni] = acc[1][ni] + rbuf[slot(1, ni, 0)] + rbuf[slot(1, ni, 2)] +
                rbuf[slot(1, ni, 3)];
  }
  __syncthreads();
#pragma unroll
  for (int ni = 0; ni < 4; ++ni) {
    rbuf[slot(0, ni, wid)] = acc[2][ni];
    rbuf[slot(1, ni, wid)] = acc[3][ni];
  }
  __syncthreads();
  if (wid == 2) {
#pragma unroll
    for (int ni = 0; ni < 4; ++ni)
      own[ni] = acc[2][ni] + rbuf[slot(0, ni, 0)] + rbuf[slot(0, ni, 1)] +
                rbuf[slot(0, ni, 3)];
  } else if (wid == 3) {
#pragma unroll
    for (int ni = 0; ni < 4; ++ni)
      own[ni] = acc[3][ni] + rbuf[slot(1, ni, 0)] + rbuf[slot(1, ni, 1)] +
                rbuf[slot(1, ni, 2)];
  }

  // ---- fused LSTM cell epilogue (wave owns M-rows [wid*16, wid*16+16)) ----
#pragma unroll
  for (int ni = 0; ni < 4; ++ni) {
    const int ncol = bn * 64 + ni * 16 + ln;
    const float bia = p.bias[ncol];
    const int j = ncol >> 2;
#pragma unroll
    for (int r = 0; r < 4; ++r) {
      float v = own[ni][r] + bia;
      float g1 = __shfl_xor(v, 1);
      float g2 = __shfl_xor(v, 2);
      float g3 = __shfl_xor(v, 3);
      int m0 = c4, m1 = c4 ^ 1, m2 = c4 ^ 2, m3 = c4 ^ 3;
      float zi = m0 == 0 ? v : (m0 == 1 ? g1 : (m0 == 2 ? g2 : g3));
      float zf = m1 == 0 ? v : (m1 == 1 ? g1 : (m1 == 2 ? g2 : g3));
      float zg = m2 == 0 ? v : (m2 == 1 ? g1 : (m2 == 2 ? g2 : g3));
      float zo = m3 == 0 ? v : (m3 == 1 ? g1 : (m3 == 2 ? g2 : g3));
      const int b = mt * 64 + wid * 16 + lm * 4 + r;
      float cp = p.c[b * 1024 + j];
      float cn = fsig(zf) * cp + fsig(zi) * ftanhf(zg);
      float hn = fsig(zo) * ftanhf(cn);
      __half h16 = __float2half(hn);
      if (c4 == 0) {
        if (p.dst0) {
          int col = p.off0 + j;
          p.dst0[(size_t)(col >> 3) * 2048 + b * 8 + (col & 7)] = h16;
        }
      } else if (c4 == 1) {
        if (p.dst1) {
          int col = p.off1 + j;
          p.dst1[(size_t)(col >> 3) * 2048 + b * 8 + (col & 7)] = h16;
        }
      } else if (c4 == 2) {
        if (p.dst2) {
          int col = p.off2 + j;
          p.dst2[(size_t)(col >> 3) * 2048 + b * 8 + (col & 7)] = h16;
        }
      } else {
        p.c[b * 1024 + j] = cn;
        if (p.feat) p.feat[(size_t)b * 3072 + p.featoff + j] = h16;
      }
    }
  }
}

// Repack weights fp32->fp16 into MFMA-fragment order:
// dst[((nt*nKt + kt)*4 + wid)*2048 + ni*512 + lane*8 + e] = W[n][k], where
// n = nt*64 + ni*16 + (lane&15) (gate-interleaved src), k = kt*128 + wid*32
// + (lane>>4)*8 + e, columns = [x pad fpad | ih-h (hih) | hh 1024].
__global__ void pack_w(__half* dst, const float* Wih, const float* Whh,
                       float* bdst, const float* bih, const float* bhh,
                       int f, int fpad, int hih, int Ktot) {
  long long i = (long long)blockIdx.x * 256 + threadIdx.x;
  long long tot = (long long)4096 * Ktot;
  const int nKt = Ktot >> 7;
  if (i < tot) {
    int q = (int)(i >> 11);
    int wid = q & 3;
    int p2 = q >> 2;
    int ktile = p2 % nKt, nt = p2 / nKt;
    int r = (int)(i & 2047);
    int ni = r >> 9, lane = (r >> 3) & 63, e = r & 7;
    int n = nt * 64 + ni * 16 + (lane & 15);
    int nsrc = (n & 3) * 1024 + (n >> 2);
    int k = ktile * 128 + wid * 32 + (lane >> 4) * 8 + e;
    float v;
    if (k < fpad)
      v = (k < f) ? Wih[(size_t)nsrc * (f + hih) + k] : 0.f;
    else if (k < fpad + hih)
      v = Wih[(size_t)nsrc * (f + hih) + f + (k - fpad)];
    else
      v = Whh[(size_t)nsrc * 1024 + (k - fpad - hih)];
    dst[i] = __float2half(v);
  }
  if (i < 4096) {
    int nsrc = ((int)i & 3) * 1024 + ((int)i >> 2);
    bdst[i] = bih[nsrc] + bhh[nsrc];
  }
}

// x [B=256][S=128][f] fp32 -> chunked fp16 [S][fpad/8][256][8], zero-padded.
__global__ void pack_x(__half* dst, const float* x, int f, int fpad) {
  long long i = (long long)blockIdx.x * 256 + threadIdx.x;
  long long tot = (long long)128 * 256 * fpad;
  if (i >= tot) return;
  int e = (int)(i & 7);
  long long u = i >> 3;
  int b = (int)(u & 255);
  long long v = u >> 8;
  int nq = fpad >> 3;
  int kq = (int)(v % nq);
  int t = (int)(v / nq);
  int k = kq * 8 + e;
  dst[i] = (k < f) ? __float2half(x[((size_t)b * 128 + t) * f + k])
                   : __float2half(0.f);
}

// out[b] = feat[b,:] . Wd + bd
__global__ void final_dot(const __half* feat, const float* Wd, const float* bd,
                          float* out) {
  int b = blockIdx.x, tid = threadIdx.x;
  float s = 0.f;
  for (int j = tid; j < 3072; j += 256)
    s += __half2float(feat[(size_t)b * 3072 + j]) * Wd[j];
  __shared__ float red[256];
  red[tid] = s;
  __syncthreads();
  for (int o = 128; o > 0; o >>= 1) {
    if (tid < o) red[tid] += red[tid + o];
    __syncthreads();
  }
  if (tid == 0) out[b] = red[0] + bd[0];
}

extern "C" void kernel_launch(void* const* d_in, const int* in_sizes, int n_in,
                              void* d_out, int out_size, void* d_ws, size_t ws_size,
                              hipStream_t stream) {
  const int B = 256, S = 128, H = 1024, NG = 4096;
  const int FRAW[3] = {300, 35, 74};
  const int FPAD[3] = {384, 128, 128};  // multiples of 128

  const float* xin[3] = {(const float*)d_in[0], (const float*)d_in[1],
                         (const float*)d_in[2]};
  const float *Wih0[3], *Whh0[3], *bih0[3], *bhh0[3];
  const float *Wih1[3], *Whh1[3], *bih1[3], *bhh1[3];
  for (int m = 0; m < 3; ++m) {
    int bidx = 3 + m * 8;
    Wih0[m] = (const float*)d_in[bidx + 0];
    Whh0[m] = (const float*)d_in[bidx + 1];
    bih0[m] = (const float*)d_in[bidx + 2];
    bhh0[m] = (const float*)d_in[bidx + 3];
    Wih1[m] = (const float*)d_in[bidx + 4];
    Whh1[m] = (const float*)d_in[bidx + 5];
    bih1[m] = (const float*)d_in[bidx + 6];
    bhh1[m] = (const float*)d_in[bidx + 7];
  }
  const float* Wd = (const float*)d_in[27];
  const float* bd = (const float*)d_in[28];

  uint8_t* wsb = (uint8_t*)d_ws;
  size_t off = 0;
  auto alloc = [&](size_t bytes) -> void* {
    void* p = wsb + off;
    off += (bytes + 255) & ~(size_t)255;
    return p;
  };

  __half* W0[3];
  __half* W1[3];
  int K0[3];
  for (int m = 0; m < 3; ++m) {
    K0[m] = FPAD[m] + 3 * H;
    W0[m] = (__half*)alloc((size_t)NG * K0[m] * 2);
  }
  for (int m = 0; m < 3; ++m) W1[m] = (__half*)alloc((size_t)NG * 2 * H * 2);
  float* biasB = (float*)alloc((size_t)6 * NG * 4);
  __half* X16[3];
  for (int m = 0; m < 3; ++m)
    X16[m] = (__half*)alloc((size_t)S * B * FPAD[m] * 2);
  size_t stateStart = off;
  __half* In0[3];
  __half* In1[3];
  for (int m = 0; m < 3; ++m) In0[m] = (__half*)alloc((size_t)2 * B * 3072 * 2);
  for (int m = 0; m < 3; ++m) In1[m] = (__half*)alloc((size_t)2 * B * 2048 * 2);
  float* cbuf = (float*)alloc((size_t)6 * B * H * 4);
  size_t stateEnd = off;
  __half* featB = (__half*)alloc((size_t)B * 3072 * 2);

  if (off > ws_size) return;

  // ---- one-time prep (every call; deterministic) ----
  for (int m = 0; m < 3; ++m) {
    long long tot0 = (long long)NG * K0[m];
    pack_w<<<dim3((unsigned)((tot0 + 255) / 256)), 256, 0, stream>>>(
        W0[m], Wih0[m], Whh0[m], biasB + m * NG, bih0[m], bhh0[m],
        FRAW[m], FPAD[m], 2 * H, K0[m]);
    long long tot1 = (long long)NG * 2 * H;
    pack_w<<<dim3((unsigned)((tot1 + 255) / 256)), 256, 0, stream>>>(
        W1[m], Wih1[m], Whh1[m], biasB + (3 + m) * NG, bih1[m], bhh1[m],
        0, 0, H, 2 * H);
    long long totx = (long long)S * B * FPAD[m];
    pack_x<<<dim3((unsigned)((totx + 255) / 256)), 256, 0, stream>>>(
        X16[m], xin[m], FRAW[m], FPAD[m]);
  }
  hipMemsetAsync(wsb + stateStart, 0, stateEnd - stateStart, stream);

  // ---- recurrent loop: 2 phase kernels per step ----
  for (int t = 0; t < S; ++t) {
    int pq = t & 1;
    __half* in0cur[3], *in0nxt[3], *in1cur[3], *in1nxt[3];
    for (int m = 0; m < 3; ++m) {
      in0cur[m] = In0[m] + (size_t)pq * B * 3072;
      in0nxt[m] = In0[m] + (size_t)(pq ^ 1) * B * 3072;
      in1cur[m] = In1[m] + (size_t)pq * B * 2048;
      in1nxt[m] = In1[m] + (size_t)(pq ^ 1) * B * 2048;
    }

    PhaseParams PA;
    for (int m = 0; m < 3; ++m) {
      ModParam& q = PA.m[m];
      q.xseg = X16[m] + (size_t)t * B * FPAD[m];
      q.Kx = FPAD[m];
      q.inseg = in0cur[m];
      q.Kin = 3072;
      q.W = W0[m];
      q.bias = biasB + m * NG;
      q.c = cbuf + (size_t)m * B * H;
      q.dst0 = in1cur[m]; q.off0 = 0;      // -> layer1 input (this step)
      q.dst1 = in0nxt[m]; q.off1 = 2048;   // -> own h0 slot (next step)
      q.dst2 = nullptr;   q.off2 = 0;
      q.feat = nullptr;   q.featoff = 0;
    }
    lstm_phase<<<dim3(768), 256, 0, stream>>>(PA);

    PhaseParams PB;
    for (int m = 0; m < 3; ++m) {
      ModParam& q = PB.m[m];
      q.xseg = nullptr; q.Kx = 0;
      q.inseg = in1cur[m]; q.Kin = 2048;
      q.W = W1[m];
      q.bias = biasB + (3 + m) * NG;
      q.c = cbuf + (size_t)(3 + m) * B * H;
      q.feat = (t == S - 1) ? featB : nullptr;
      q.featoff = m * H;
      if (m == 0) {        // h1_t -> In0_v[:,0], In0_a[:,0], In1_t[:,1024]
        q.dst0 = in0nxt[1]; q.off0 = 0;
        q.dst1 = in0nxt[2]; q.off1 = 0;
        q.dst2 = in1nxt[0]; q.off2 = 1024;
      } else if (m == 1) { // h1_v -> In0_t[:,0], In0_a[:,1024], In1_v[:,1024]
        q.dst0 = in0nxt[0]; q.off0 = 0;
        q.dst1 = in0nxt[2]; q.off1 = 1024;
        q.dst2 = in1nxt[1]; q.off2 = 1024;
      } else {             // h1_a -> In0_t[:,1024], In0_v[:,1024], In1_a[:,1024]
        q.dst0 = in0nxt[0]; q.off0 = 1024;
        q.dst1 = in0nxt[1]; q.off1 = 1024;
        q.dst2 = in1nxt[2]; q.off2 = 1024;
      }
    }
    lstm_phase<<<dim3(768), 256, 0, stream>>>(PB);
  }

  final_dot<<<dim3(256), 256, 0, stream>>>(featB, Wd, bd, (float*)d_out);
}